// Round 1
// baseline (606.106 us; speedup 1.0000x reference)
//
#include <hip/hip_runtime.h>
#include <hip/hip_bf16.h>
#include <math.h>

#define NN 65536
#define MM 32
#define KK 32

#define HALF_LOG_2PI 0.91893853320467274178f
#define L2E 1.44269504088896340736f
#define TTG_EPS 2.2204460492503131e-16f

static __device__ __forceinline__ float fast_exp2(float x) {
#if __has_builtin(__builtin_amdgcn_exp2f)
  return __builtin_amdgcn_exp2f(x);
#else
  return exp2f(x);
#endif
}

// ws layout (floats): [0..31] softmax(wk0) ; [64 ...] params as float4[M*1024]
// param index: ((i*4 + kl)*32 + j)*8 + kp   for k = kp*4 + kl
// Per element: exp-argument (base 2) = P0 + P1*x + P2*x^2.
__global__ void ttg_precompute(const float* __restrict__ wk0_logits,
                               const float* __restrict__ W_logits,
                               const float* __restrict__ mu,
                               const float* __restrict__ pre_sigma,
                               float* __restrict__ ws) {
  int i = blockIdx.x;  // 0..31
  __shared__ float wsl[1024];
  __shared__ float lse[32];
  for (int t = threadIdx.x; t < 1024; t += blockDim.x)
    wsl[t] = W_logits[i * 1024 + t];
  __syncthreads();
  if (threadIdx.x < 32) {
    int j = threadIdx.x;
    float mx = -1e30f;
    for (int k = 0; k < 32; ++k) mx = fmaxf(mx, wsl[k * 32 + j]);
    float s = 0.f;
    for (int k = 0; k < 32; ++k) s += expf(wsl[k * 32 + j] - mx);
    lse[j] = mx + logf(s);
  }
  __syncthreads();
  float4* params = (float4*)(ws + 64);
  for (int t = threadIdx.x; t < 1024; t += blockDim.x) {
    int k = t >> 5, j = t & 31;
    float ps = pre_sigma[t];
    float sg = log1pf(expf(-fabsf(ps))) + fmaxf(ps, 0.f);  // softplus
    float a = 1.f / sg;
    float b = mu[t] * a;
    float lw = wsl[t] - lse[j];
    float c = lw - logf(sg) - HALF_LOG_2PI;
    float P0 = (c - 0.5f * b * b) * L2E;
    float P1 = (a * b) * L2E;
    float P2 = (-0.5f * a * a) * L2E;
    int kl = k & 3, kp = k >> 2;
    params[i * 1024 + (kl * 32 + j) * 8 + kp] = make_float4(P0, P1, P2, 0.f);
  }
  if (i == 0 && threadIdx.x < 32) {
    float mx = -1e30f;
    for (int j = 0; j < 32; ++j) mx = fmaxf(mx, wk0_logits[j]);
    float s = 0.f;
    for (int j = 0; j < 32; ++j) s += expf(wk0_logits[j] - mx);
    ws[threadIdx.x] = expf(wk0_logits[threadIdx.x] - mx) / s;
  }
}

// block = 512 threads: kp = t&7 (k-part, 4 k's each), sl = t>>3 (sample slot 0..63)
// each thread handles 2 samples: n0 = blk*128 + sl, n1 = n0 + 64
__global__ __launch_bounds__(512, 4) void ttg_main(const float* __restrict__ X,
                                                   const float* __restrict__ ws,
                                                   float* __restrict__ out) {
  __shared__ float4 pbuf[2][1024];                 // 32 KB: per-step params, double-buffered
  __shared__ __align__(16) float vbuf[2][128][36]; // 36 KB: v exchange, padded rows (36 floats)
  const float4* params = (const float4*)(ws + 64);
  const int t = threadIdx.x;
  const int kp = t & 7;
  const int sl = t >> 3;
  const int n0 = blockIdx.x * 128 + sl;
  const int n1 = n0 + 64;

  float v0[32], v1[32];
#pragma unroll
  for (int j = 0; j < 32; ++j) {
    float w = ws[j];
    v0[j] = w;
    v1[j] = w;
  }

  // stage step-0 params
  {
    float4 a = params[t];
    float4 b = params[t + 512];
    pbuf[0][t] = a;
    pbuf[0][t + 512] = b;
  }
  __syncthreads();

  float part0 = 0.f, part1 = 0.f;

  for (int i = 0; i < 32; ++i) {
    // prefetch next step's params into registers (written to LDS after compute)
    float4 pa, pb;
    if (i < 31) {
      const float4* src = params + (i + 1) * 1024;
      pa = src[t];
      pb = src[t + 512];
    }
    float x0 = X[n0 * MM + i];
    float x1 = X[n1 * MM + i];
    float x0s = x0 * x0, x1s = x1 * x1;
    const float4* pcur = pbuf[i & 1];

    float nv0[4], nv1[4];
#pragma unroll
    for (int kl = 0; kl < 4; ++kl) {
      float a0 = 0.f, a1 = 0.f;
#pragma unroll
      for (int j = 0; j < 32; ++j) {
        float4 p = pcur[(kl * 32 + j) * 8 + kp];  // 8 distinct 16B addrs, 128B contig: conflict-free broadcast
        float g0 = fmaf(p.z, x0s, fmaf(p.y, x0, p.x));
        float g1 = fmaf(p.z, x1s, fmaf(p.y, x1, p.x));
        float r0 = fast_exp2(g0);
        float r1 = fast_exp2(g1);
        a0 = fmaf(v0[j], r0, a0);
        a1 = fmaf(v1[j], r1, a1);
      }
      nv0[kl] = a0;
      nv1[kl] = a1;
    }

    if (i < 31) {
      // publish new v slice, stage prefetched params, one barrier, reload full v rows
      *(float4*)&vbuf[i & 1][sl][kp * 4] = make_float4(nv0[0], nv0[1], nv0[2], nv0[3]);
      *(float4*)&vbuf[i & 1][sl + 64][kp * 4] = make_float4(nv1[0], nv1[1], nv1[2], nv1[3]);
      pbuf[(i + 1) & 1][t] = pa;
      pbuf[(i + 1) & 1][t + 512] = pb;
      __syncthreads();
#pragma unroll
      for (int jc = 0; jc < 8; ++jc) {
        float4 r0 = *(const float4*)&vbuf[i & 1][sl][jc * 4];
        float4 r1 = *(const float4*)&vbuf[i & 1][sl + 64][jc * 4];
        v0[jc * 4 + 0] = r0.x; v0[jc * 4 + 1] = r0.y; v0[jc * 4 + 2] = r0.z; v0[jc * 4 + 3] = r0.w;
        v1[jc * 4 + 0] = r1.x; v1[jc * 4 + 1] = r1.y; v1[jc * 4 + 2] = r1.z; v1[jc * 4 + 3] = r1.w;
      }
    } else {
      part0 = nv0[0] + nv0[1] + nv0[2] + nv0[3];
      part1 = nv1[0] + nv1[1] + nv1[2] + nv1[3];
    }
  }

  // reduce partial sums over the 8 k-parts (lanes t&7 within each 8-lane group)
  for (int m = 1; m < 8; m <<= 1) {
    part0 += __shfl_xor(part0, m);
    part1 += __shfl_xor(part1, m);
  }
  if (kp == 0) {
    out[n0] = logf(part0 + TTG_EPS);
    out[n1] = logf(part1 + TTG_EPS);
  }
}

extern "C" void kernel_launch(void* const* d_in, const int* in_sizes, int n_in,
                              void* d_out, int out_size, void* d_ws, size_t ws_size,
                              hipStream_t stream) {
  const float* X          = (const float*)d_in[0];
  const float* wk0_logits = (const float*)d_in[1];
  const float* W_logits   = (const float*)d_in[2];
  const float* mu         = (const float*)d_in[3];
  const float* pre_sigma  = (const float*)d_in[4];
  float* out = (float*)d_out;
  float* ws  = (float*)d_ws;

  ttg_precompute<<<32, 256, 0, stream>>>(wk0_logits, W_logits, mu, pre_sigma, ws);
  ttg_main<<<512, 512, 0, stream>>>(X, ws, out);
}

// Round 2
// 357.905 us; speedup vs baseline: 1.6935x; 1.6935x over previous
//
#include <hip/hip_runtime.h>
#include <hip/hip_bf16.h>
#include <math.h>

#define NN 65536
#define MM 32
#define KK 32

#define HALF_LOG_2PI 0.91893853320467274178f
#define L2E 1.44269504088896340736f
#define TTG_EPS 2.2204460492503131e-16f

static __device__ __forceinline__ float fast_exp2(float x) {
#if __has_builtin(__builtin_amdgcn_exp2f)
  return __builtin_amdgcn_exp2f(x);
#else
  return exp2f(x);
#endif
}

// ws layout (floats):
//   [0..31]   softmax(wk0)
//   [64 ...]  params as float4, plane layout:
//             float4 index = ((i*3 + p)*8 + jq)*32 + k,  component = j&3  (j = jq*4 + jc)
//             p: 0=P0, 1=P1, 2=P2.  exp2-argument = P0 + P1*x + P2*x^2.
__global__ void ttg_precompute(const float* __restrict__ wk0_logits,
                               const float* __restrict__ W_logits,
                               const float* __restrict__ mu,
                               const float* __restrict__ pre_sigma,
                               float* __restrict__ ws) {
  int i = blockIdx.x;  // 0..31
  __shared__ float wsl[1024];
  __shared__ float lse[32];
  for (int t = threadIdx.x; t < 1024; t += blockDim.x)
    wsl[t] = W_logits[i * 1024 + t];
  __syncthreads();
  if (threadIdx.x < 32) {
    int j = threadIdx.x;
    float mx = -1e30f;
    for (int k = 0; k < 32; ++k) mx = fmaxf(mx, wsl[k * 32 + j]);
    float s = 0.f;
    for (int k = 0; k < 32; ++k) s += expf(wsl[k * 32 + j] - mx);
    lse[j] = mx + logf(s);
  }
  __syncthreads();
  float* params = ws + 64;
  for (int t = threadIdx.x; t < 1024; t += blockDim.x) {
    int k = t >> 5, j = t & 31;
    float ps = pre_sigma[t];
    float sg = log1pf(expf(-fabsf(ps))) + fmaxf(ps, 0.f);  // softplus
    float a = 1.f / sg;
    float b = mu[t] * a;
    float lw = wsl[t] - lse[j];
    float c = lw - logf(sg) - HALF_LOG_2PI;
    float P0 = (c - 0.5f * b * b) * L2E;
    float P1 = (a * b) * L2E;
    float P2 = (-0.5f * a * a) * L2E;
    int jq = j >> 2, jc = j & 3;
    params[((((i * 3 + 0) * 8 + jq) * 32) + k) * 4 + jc] = P0;
    params[((((i * 3 + 1) * 8 + jq) * 32) + k) * 4 + jc] = P1;
    params[((((i * 3 + 2) * 8 + jq) * 32) + k) * 4 + jc] = P2;
  }
  if (i == 0 && threadIdx.x < 32) {
    float mx = -1e30f;
    for (int j = 0; j < 32; ++j) mx = fmaxf(mx, wk0_logits[j]);
    float s = 0.f;
    for (int j = 0; j < 32; ++j) s += expf(wk0_logits[j] - mx);
    ws[threadIdx.x] = expf(wk0_logits[threadIdx.x] - mx) / s;
  }
}

// 256 threads = 4 independent waves. Each wave owns 16 samples; no __syncthreads.
// Lane L: k = L&31 (output row), sh = L>>5 (sample parity). Pair iteration tt
// processes samples (2tt, 2tt+1) concurrently across the two half-waves.
// Params for row k held in 96 VGPRs, reloaded per step from L2 (coalesced).
// v[32] per sample lives in wave-private LDS; wave-lockstep in-order DS ops
// make single-buffering safe.
__global__ __launch_bounds__(256, 3) void ttg_main(const float* __restrict__ X,
                                                   const float* __restrict__ ws,
                                                   float* __restrict__ out) {
  __shared__ __align__(16) float vbuf[4][16][32];    // [wave][sample][k]  8 KB
  __shared__ __align__(8)  float2 xbuf[4][16][32];   // [wave][sample][i] = (x, x^2)  16 KB
  const int t = threadIdx.x;
  const int wv = t >> 6;
  const int L = t & 63;
  const int k = L & 31;
  const int sh = L >> 5;
  const int n0 = (blockIdx.x * 4 + wv) * 16;

  // stage x (+x^2), fully coalesced: flat f = n-local*32 + i
  for (int r = 0; r < 8; ++r) {
    int f = L + 64 * r;  // 0..511
    int s = f >> 5, i = f & 31;
    float x = X[n0 * 32 + f];
    xbuf[wv][s][i] = make_float2(x, x * x);
  }
  // init v = softmax(wk0)
  {
    float w0 = ws[k];
#pragma unroll
    for (int rep = 0; rep < 8; ++rep)
      vbuf[wv][rep * 2 + sh][k] = w0;
  }

  const float4* __restrict__ P = (const float4*)(ws + 64);

  for (int i = 0; i < 32; ++i) {
    const float4* Pi = P + i * 768 + k;
    float4 p0[8], p1[8], p2[8];
#pragma unroll
    for (int jq = 0; jq < 8; ++jq) {
      p0[jq] = Pi[jq * 32];
      p1[jq] = Pi[256 + jq * 32];
      p2[jq] = Pi[512 + jq * 32];
    }
#pragma unroll
    for (int tt = 0; tt < 8; ++tt) {
      const int s = tt * 2 + sh;
      float2 xx = xbuf[wv][s][i];      // broadcast (2 distinct addrs/wave)
      float acc = 0.f;
#pragma unroll
      for (int jq = 0; jq < 8; ++jq) {
        float4 v4 = *(const float4*)&vbuf[wv][s][jq * 4];  // broadcast b128
        acc = fmaf(v4.x, fast_exp2(fmaf(p2[jq].x, xx.y, fmaf(p1[jq].x, xx.x, p0[jq].x))), acc);
        acc = fmaf(v4.y, fast_exp2(fmaf(p2[jq].y, xx.y, fmaf(p1[jq].y, xx.x, p0[jq].y))), acc);
        acc = fmaf(v4.z, fast_exp2(fmaf(p2[jq].z, xx.y, fmaf(p1[jq].z, xx.x, p0[jq].z))), acc);
        acc = fmaf(v4.w, fast_exp2(fmaf(p2[jq].w, xx.y, fmaf(p1[jq].w, xx.x, p0[jq].w))), acc);
      }
      // all reads of row s (this step) precede this write in wave program order
      vbuf[wv][s][k] = acc;
    }
  }

  // output: per sample, sum v over k, log(+eps). Butterfly stays within half-waves.
#pragma unroll
  for (int tt = 0; tt < 8; ++tt) {
    const int s = tt * 2 + sh;
    float val = vbuf[wv][s][k];
    val += __shfl_xor(val, 1);
    val += __shfl_xor(val, 2);
    val += __shfl_xor(val, 4);
    val += __shfl_xor(val, 8);
    val += __shfl_xor(val, 16);
    if (k == 0) out[n0 + s] = logf(val + TTG_EPS);
  }
}

extern "C" void kernel_launch(void* const* d_in, const int* in_sizes, int n_in,
                              void* d_out, int out_size, void* d_ws, size_t ws_size,
                              hipStream_t stream) {
  const float* X          = (const float*)d_in[0];
  const float* wk0_logits = (const float*)d_in[1];
  const float* W_logits   = (const float*)d_in[2];
  const float* mu         = (const float*)d_in[3];
  const float* pre_sigma  = (const float*)d_in[4];
  float* out = (float*)d_out;
  float* ws  = (float*)d_ws;

  ttg_precompute<<<32, 256, 0, stream>>>(wk0_logits, W_logits, mu, pre_sigma, ws);
  ttg_main<<<1024, 256, 0, stream>>>(X, ws, out);
}

// Round 4
// 341.938 us; speedup vs baseline: 1.7726x; 1.0467x over previous
//
#include <hip/hip_runtime.h>
#include <hip/hip_bf16.h>
#include <math.h>

#define NN 65536
#define MM 32
#define KK 32

#define HALF_LOG_2PI 0.91893853320467274178f
#define L2E 1.44269504088896340736f
#define TTG_EPS 2.2204460492503131e-16f

static __device__ __forceinline__ float fast_exp2(float x) {
#if __has_builtin(__builtin_amdgcn_exp2f)
  return __builtin_amdgcn_exp2f(x);
#else
  return exp2f(x);
#endif
}

// ws layout (floats):
//   [0..31]   softmax(wk0)
//   [64 ...]  params as float4, plane layout:
//             float4 index = ((i*3 + p)*8 + jq)*32 + k,  component = j&3  (j = jq*4 + jc)
//             p: 0=P0, 1=P1, 2=P2.  exp2-argument = P0 + P1*x + P2*x^2.
__global__ void ttg_precompute(const float* __restrict__ wk0_logits,
                               const float* __restrict__ W_logits,
                               const float* __restrict__ mu,
                               const float* __restrict__ pre_sigma,
                               float* __restrict__ ws) {
  int i = blockIdx.x;  // 0..31
  __shared__ float wsl[1024];
  __shared__ float lse[32];
  for (int t = threadIdx.x; t < 1024; t += blockDim.x)
    wsl[t] = W_logits[i * 1024 + t];
  __syncthreads();
  if (threadIdx.x < 32) {
    int j = threadIdx.x;
    float mx = -1e30f;
    for (int k = 0; k < 32; ++k) mx = fmaxf(mx, wsl[k * 32 + j]);
    float s = 0.f;
    for (int k = 0; k < 32; ++k) s += expf(wsl[k * 32 + j] - mx);
    lse[j] = mx + logf(s);
  }
  __syncthreads();
  float* params = ws + 64;
  for (int t = threadIdx.x; t < 1024; t += blockDim.x) {
    int k = t >> 5, j = t & 31;
    float ps = pre_sigma[t];
    float sg = log1pf(expf(-fabsf(ps))) + fmaxf(ps, 0.f);  // softplus
    float a = 1.f / sg;
    float b = mu[t] * a;
    float lw = wsl[t] - lse[j];
    float c = lw - logf(sg) - HALF_LOG_2PI;
    float P0 = (c - 0.5f * b * b) * L2E;
    float P1 = (a * b) * L2E;
    float P2 = (-0.5f * a * a) * L2E;
    int jq = j >> 2, jc = j & 3;
    params[((((i * 3 + 0) * 8 + jq) * 32) + k) * 4 + jc] = P0;
    params[((((i * 3 + 1) * 8 + jq) * 32) + k) * 4 + jc] = P1;
    params[((((i * 3 + 2) * 8 + jq) * 32) + k) * 4 + jc] = P2;
  }
  if (i == 0 && threadIdx.x < 32) {
    float mx = -1e30f;
    for (int j = 0; j < 32; ++j) mx = fmaxf(mx, wk0_logits[j]);
    float s = 0.f;
    for (int j = 0; j < 32; ++j) s += expf(wk0_logits[j] - mx);
    ws[threadIdx.x] = expf(wk0_logits[threadIdx.x] - mx) / s;
  }
}

// 256 threads = 4 independent waves, no __syncthreads in the main loop.
// Lane L: k = L&31 (output row), sh = L>>5. Wave owns 16 samples; per pair-slot
// tt the two half-waves process samples 2tt and 2tt+1.
// j-loop split in two halves of 4 quads so only 48 param VGPRs are live at a
// time (fits the 128-VGPR / 16-waves-per-CU budget; round-2's 96-float block
// was silently rematerialized at VGPR_Count=64).
__global__ __launch_bounds__(256, 4) void ttg_main(const float* __restrict__ X,
                                                   const float* __restrict__ ws,
                                                   float* __restrict__ out) {
  __shared__ __align__(16) float vbuf[4][16][32];    // [wave][sample][k]  8 KB
  __shared__ __align__(8)  float2 xbuf[4][16][32];   // [wave][sample][i] = (x, x^2)  16 KB
  const int t = threadIdx.x;
  const int wv = t >> 6;
  const int L = t & 63;
  const int k = L & 31;
  const int sh = L >> 5;
  const int n0 = (blockIdx.x * 4 + wv) * 16;

  // stage x (+x^2), fully coalesced
  for (int r = 0; r < 8; ++r) {
    int f = L + 64 * r;  // 0..511
    int s = f >> 5, i = f & 31;
    float x = X[n0 * 32 + f];
    xbuf[wv][s][i] = make_float2(x, x * x);
  }
  // init v = softmax(wk0)
  {
    float w0 = ws[k];
#pragma unroll
    for (int rep = 0; rep < 8; ++rep)
      vbuf[wv][rep * 2 + sh][k] = w0;
  }

  const float4* __restrict__ P = (const float4*)(ws + 64);

  for (int i = 0; i < 32; ++i) {
    const float4* Pi = P + i * 768 + k;
    float4 q0[4], q1[4], q2[4];
    float acc[8];

    // ---- half A: j-quads 0..3 ----
#pragma unroll
    for (int jq = 0; jq < 4; ++jq) {
      q0[jq] = Pi[jq * 32];
      q1[jq] = Pi[256 + jq * 32];
      q2[jq] = Pi[512 + jq * 32];
    }
#pragma unroll
    for (int tt = 0; tt < 8; ++tt) {
      const int s = tt * 2 + sh;
      float2 xx = xbuf[wv][s][i];
      float a = 0.f;
#pragma unroll
      for (int jq = 0; jq < 4; ++jq) {
        float4 v4 = *(const float4*)&vbuf[wv][s][jq * 4];  // broadcast b128
        a = fmaf(v4.x, fast_exp2(fmaf(q2[jq].x, xx.y, fmaf(q1[jq].x, xx.x, q0[jq].x))), a);
        a = fmaf(v4.y, fast_exp2(fmaf(q2[jq].y, xx.y, fmaf(q1[jq].y, xx.x, q0[jq].y))), a);
        a = fmaf(v4.z, fast_exp2(fmaf(q2[jq].z, xx.y, fmaf(q1[jq].z, xx.x, q0[jq].z))), a);
        a = fmaf(v4.w, fast_exp2(fmaf(q2[jq].w, xx.y, fmaf(q1[jq].w, xx.x, q0[jq].w))), a);
      }
      acc[tt] = a;
    }

    // ---- half B: j-quads 4..7 ----
#pragma unroll
    for (int jq = 0; jq < 4; ++jq) {
      q0[jq] = Pi[(jq + 4) * 32];
      q1[jq] = Pi[256 + (jq + 4) * 32];
      q2[jq] = Pi[512 + (jq + 4) * 32];
    }
#pragma unroll
    for (int tt = 0; tt < 8; ++tt) {
      const int s = tt * 2 + sh;
      float2 xx = xbuf[wv][s][i];
      float a = acc[tt];
#pragma unroll
      for (int jq = 0; jq < 4; ++jq) {
        float4 v4 = *(const float4*)&vbuf[wv][s][(jq + 4) * 4];
        a = fmaf(v4.x, fast_exp2(fmaf(q2[jq].x, xx.y, fmaf(q1[jq].x, xx.x, q0[jq].x))), a);
        a = fmaf(v4.y, fast_exp2(fmaf(q2[jq].y, xx.y, fmaf(q1[jq].y, xx.x, q0[jq].y))), a);
        a = fmaf(v4.z, fast_exp2(fmaf(q2[jq].z, xx.y, fmaf(q1[jq].z, xx.x, q0[jq].z))), a);
        a = fmaf(v4.w, fast_exp2(fmaf(q2[jq].w, xx.y, fmaf(q1[jq].w, xx.x, q0[jq].w))), a);
      }
      acc[tt] = a;
    }

    if (i < 31) {
      // publish new v; all reads of step i precede these writes in wave
      // program order, and step i+1's reads follow them (in-order DS pipe).
#pragma unroll
      for (int tt = 0; tt < 8; ++tt)
        vbuf[wv][tt * 2 + sh][k] = acc[tt];
    } else {
      // final step: reduce over k within each half-wave and emit
#pragma unroll
      for (int tt = 0; tt < 8; ++tt) {
        float val = acc[tt];
        val += __shfl_xor(val, 1);
        val += __shfl_xor(val, 2);
        val += __shfl_xor(val, 4);
        val += __shfl_xor(val, 8);
        val += __shfl_xor(val, 16);
        if (k == 0) out[n0 + tt * 2 + sh] = logf(val + TTG_EPS);
      }
    }
  }
}

extern "C" void kernel_launch(void* const* d_in, const int* in_sizes, int n_in,
                              void* d_out, int out_size, void* d_ws, size_t ws_size,
                              hipStream_t stream) {
  const float* X          = (const float*)d_in[0];
  const float* wk0_logits = (const float*)d_in[1];
  const float* W_logits   = (const float*)d_in[2];
  const float* mu         = (const float*)d_in[3];
  const float* pre_sigma  = (const float*)d_in[4];
  float* out = (float*)d_out;
  float* ws  = (float*)d_ws;

  ttg_precompute<<<32, 256, 0, stream>>>(wk0_logits, W_logits, mu, pre_sigma, ws);
  ttg_main<<<1024, 256, 0, stream>>>(X, ws, out);
}